// Round 23
// baseline (124.662 us; speedup 1.0000x reference)
//
#include <hip/hip_runtime.h>
#include <hip/hip_bf16.h>
#include <hip/hip_fp8.h>

#define HEADS 16
#define B_    8
#define H_    2048
#define L_    1024
#define DK    128   // H_/HEADS

typedef __attribute__((ext_vector_type(8))) int   i32x8;
typedef __attribute__((ext_vector_type(4))) int   i32x4;
typedef __attribute__((ext_vector_type(4))) float f32x4;

__device__ __forceinline__ unsigned u8e4m3(float x) {
  __hip_fp8_e4m3 f8(x);
  return (unsigned)f8.__x;
}

// async global->LDS, 16 B per lane: global src per-lane, LDS dest wave-uniform
__device__ __forceinline__ void gload_lds16(const void* g, void* l) {
  __builtin_amdgcn_global_load_lds(
      (const __attribute__((address_space(1))) void*)g,
      (__attribute__((address_space(3))) void*)l, 16, 0, 0);
}

// ---------------------------------------------------------------------------
// Kernel 0 (merged preps).
// Blocks 0..127:   qs2[bh][j] = { 64*(q.Wq + bias)[j], score[j]/64 }  (float2)
// Blocks 128..143: wk8 fp8-fragment pack of 64*Wk (e4m3):
//   lane-slot (nc, l): n = nc*16 + (l&15), k = (l>>4)*32 + i (i=0..31)
//   storage: wk8[nc*2048 + (i<16?0:1024) + l*16 + (i&15)]
// ---------------------------------------------------------------------------
__global__ void __launch_bounds__(256)
prep_kernel(const float* __restrict__ query,
            const float* __restrict__ attn_w,
            const float* __restrict__ bias,
            const float* __restrict__ score,
            float2* __restrict__ qs2,
            unsigned char* __restrict__ wk8) {
  const int tid = threadIdx.x;
  if (blockIdx.x < 128) {
    const int jt = blockIdx.x & 7;    // j-tile
    const int bg = blockIdx.x >> 3;   // bh-group of 8
    __shared__ float qv[8][DK];
    for (int i = tid; i < 8 * DK; i += 256) {
      const int bh = bg * 8 + (i >> 7);
      const int d  = i & 127;
      const int b = bh >> 4, head = bh & 15;
      qv[i >> 7][d] = query[b * H_ + head * DK + d];
    }
    __syncthreads();
    const int j = jt * 256 + tid;
    const float bj = bias[j];
    const float sj = score[j] * (1.0f / 64.0f);
    float acc[8];
#pragma unroll
    for (int u = 0; u < 8; ++u) acc[u] = bj;
    for (int d = 0; d < DK; ++d) {
      const float wv = attn_w[d * H_ + j];
#pragma unroll
      for (int u = 0; u < 8; ++u) acc[u] += qv[u][d] * wv;
    }
#pragma unroll
    for (int u = 0; u < 8; ++u) {
      float2 t; t.x = 64.0f * acc[u]; t.y = sj;
      qs2[(size_t)(bg * 8 + u) * H_ + j] = t;
    }
  } else {
    const int t0 = (blockIdx.x - 128) * 256 + tid;   // 0..4095
    for (int tt = t0; tt < 8192; tt += 4096) {       // lane-slots
      const int l  = tt & 63;
      const int nc = tt >> 6;
      const int n  = nc * 16 + (l & 15);
      const int k0 = (l >> 4) * 32;
#pragma unroll
      for (int half = 0; half < 2; ++half) {
        unsigned w[4];
#pragma unroll
        for (int j = 0; j < 4; ++j) {
          unsigned v = 0;
#pragma unroll
          for (int byt = 0; byt < 4; ++byt) {
            const int i = half * 16 + j * 4 + byt;
            const float x = 64.0f * attn_w[(size_t)(DK + k0 + i) * H_ + n];
            v |= u8e4m3(x) << (8 * byt);
          }
          w[j] = v;
        }
        uint4 q; q.x = w[0]; q.y = w[1]; q.z = w[2]; q.w = w[3];
        *(uint4*)(wk8 + (size_t)nc * 2048 + half * 1024 + l * 16) = q;
      }
    }
  }
}

// ---------------------------------------------------------------------------
// Kernel 1: partial logits over one H-half (MX-fp8 K=128, scales=1.0).
// 128 ROWS PER WAVE (fp8 A = half bytes -> aF[8] = 64 VGPR fits): per 2KB B
// chunk a wave issues 8 independent full-K MFMAs (2x r22's work/acquisition;
// chunk-instances per SIMD halve). Block = 4 waves x 128 rows = 512 rows of
// one bh, one H-half (z-split). r22's proven ring schedule: 4-slot x 16KB
// ring, phase = 8 chunks (8 phases), counted vmcnt(8) + 1 raw barrier/phase.
// Plain launch_bounds(256): VGPR cap 512 (no clamp-spill; ~160 live).
// LDS 72KB -> 2 blocks/CU.
// ---------------------------------------------------------------------------
__global__ void __launch_bounds__(256)
logits_kernel(const float* __restrict__ feed,
              const unsigned char* __restrict__ wk8,
              const float2* __restrict__ qs2,
              float* __restrict__ logits) {
  const int ltile = blockIdx.x;     // 0..1 (512 rows each)
  const int bh    = blockIdx.y;     // 0..127
  const int nblk  = blockIdx.z;     // 0..1 (H halves)
  const int b     = bh >> 4;
  const int head  = bh & 15;
  const int tid   = threadIdx.x;
  const int wave  = tid >> 6;
  const int lane  = tid & 63;
  const int row   = lane & 15;      // A row / B col / D col
  const int g     = lane >> 4;      // k-group 0..3 (32 k each)

  __shared__ unsigned char ring[4][16384]; // 4 slots x 16KB (phase = 8 chunks)
  __shared__ float2 qs[1024];              // {64*qwb, score/64} half: 8 KB

  // ---- stage qs for this half (block-cooperative) ----
#pragma unroll
  for (int u = 0; u < 4; ++u)
    qs[tid + 256 * u] = qs2[(size_t)bh * H_ + nblk * 1024 + tid + 256 * u];

  // ---- A fragments: 8 subtiles (128 rows), e4m3-packed, resident (64 VGPR) ----
  i32x8 aF[8];
#pragma unroll
  for (int s = 0; s < 8; ++s) {
    const int l = ltile * 512 + wave * 128 + s * 16 + row;
    const float* fh = feed + (size_t)l * (B_ * H_) + b * H_ + head * DK + g * 32;
    i32x8 af;
#pragma unroll
    for (int j = 0; j < 8; ++j) {
      float4 x = *(const float4*)(fh + j * 4);
      unsigned v = u8e4m3(x.x) | (u8e4m3(x.y) << 8) |
                   (u8e4m3(x.z) << 16) | (u8e4m3(x.w) << 24);
      af[j] = (int)v;
    }
    aF[s] = af;
  }
  __syncthreads();   // qs visible; drains ALL prologue VMEM -> in-loop vmcnt
                     // counts only the staging gloads.

  const char* wkb   = (const char*)wk8 + (size_t)nblk * 131072;  // half base
  char*       ringb = (char*)ring;
  const int   seg0  = wave * 4096;   // this wave's 4KB segment per phase

  // ---- ring prologue: phases 0,1 into slots 0,1 (4 gloads each/wave) ----
#pragma unroll
  for (int ph = 0; ph < 2; ++ph) {
#pragma unroll
    for (int i = 0; i < 4; ++i)
      gload_lds16(wkb + (size_t)ph * 16384 + seg0 + i * 1024 + lane * 16,
                  ringb + ph * 16384 + seg0 + i * 1024);
  }

  float lacc[8][4] = {};

#pragma unroll 1
  for (int p = 0; p < 8; ++p) {
    // stage phase p+2 (4-slot ring, lookahead 2 — r7/r19/r22-proven race-free;
    // clamped tail re-issues land in slots whose readers finished >=2
    // barriers ago)
    const int pf = (p + 2 < 8) ? p + 2 : 7;
    const int ws = ((p + 2) & 3) * 16384;
#pragma unroll
    for (int i = 0; i < 4; ++i)
      gload_lds16(wkb + (size_t)pf * 16384 + seg0 + i * 1024 + lane * 16,
                  ringb + ws + seg0 + i * 1024);

    __builtin_amdgcn_sched_barrier(0);
    // own phase-p loads landed (phases p+1, p+2 = 8 loads stay in flight)
    asm volatile("s_waitcnt vmcnt(8)" ::: "memory");
    __builtin_amdgcn_s_barrier();        // all waves' phase-p loads landed
    __builtin_amdgcn_sched_barrier(0);

    const char* rs = ringb + (p & 3) * 16384;
#pragma unroll
    for (int cc = 0; cc < 8; ++cc) {
      const char* rc = rs + cc * 2048 + lane * 16;
      i32x4 lo = *(const i32x4*)(rc);
      i32x4 hi = *(const i32x4*)(rc + 1024);
      i32x8 b8;
      b8[0] = lo[0]; b8[1] = lo[1]; b8[2] = lo[2]; b8[3] = lo[3];
      b8[4] = hi[0]; b8[5] = hi[1]; b8[6] = hi[2]; b8[7] = hi[3];
      const float2 q2 = qs[(8 * p + cc) * 16 + row];
      const float qx = q2.x, qy = q2.y;

      // 8 INDEPENDENT full-K MFMAs (scales = 1.0 -> plain fp8 K=128 GEMM)
      const f32x4 dini = {qx, qx, qx, qx};
      f32x4 d[8];
#pragma unroll
      for (int s = 0; s < 8; ++s)
        d[s] = __builtin_amdgcn_mfma_scale_f32_16x16x128_f8f6f4(
                 aF[s], b8, dini, 0, 0, 0, 0x7F7F7F7F, 0, 0x7F7F7F7F);

#pragma unroll
      for (int s = 0; s < 8; ++s) {
#pragma unroll
        for (int i = 0; i < 4; ++i)
          lacc[s][i] += fmaxf(d[s][i], 0.f) * qy;
      }
    }
  }

  // ---- reduce over the 16 D-columns, write partial logits ----
#pragma unroll
  for (int s = 0; s < 8; ++s) {
#pragma unroll
    for (int i = 0; i < 4; ++i) {
      float v = lacc[s][i];
#pragma unroll
      for (int off = 1; off < 16; off <<= 1) v += __shfl_xor(v, off);
      lacc[s][i] = v;
    }
  }
  if (row == 0) {
    float* lout = logits + (size_t)nblk * (128 * L_);
#pragma unroll
    for (int s = 0; s < 8; ++s) {
      const int base = bh * L_ + ltile * 512 + wave * 128 + s * 16 + g * 4;
#pragma unroll
      for (int i = 0; i < 4; ++i) lout[base + i] = lacc[s][i];
    }
  }
}

// ---------------------------------------------------------------------------
// Kernel 2: grid (bh, dpart): softmax over L (sum of the two H-half partial
// buffers, redundant per dpart), then out[d] over 32 d-columns. float4 reads.
// (At HBM roofline for the values read — ~10.5us floor.)
// ---------------------------------------------------------------------------
__global__ void __launch_bounds__(256)
softmax_pv_kernel(const float* __restrict__ logits,
                  const float* __restrict__ values,
                  float* __restrict__ out) {
  const int bh    = blockIdx.x;   // 0..127
  const int dpart = blockIdx.y;   // 0..3  (32 d-cols each)
  const int b     = bh >> 4;
  const int head  = bh & 15;
  const int tid   = threadIdx.x;

  __shared__ float  sl[L_];
  __shared__ float  sred[4];
  __shared__ float  sscal;
  __shared__ float4 pacc[32][8];

  float m = -1e30f;
  for (int i = tid; i < L_; i += 256) {
    float v = logits[(size_t)bh * L_ + i] +
              logits[(size_t)(128 * L_) + bh * L_ + i];
    sl[i] = v;
    m = fmaxf(m, v);
  }
#pragma unroll
  for (int off = 32; off > 0; off >>= 1) m = fmaxf(m, __shfl_xor(m, off));
  if ((tid & 63) == 0) sred[tid >> 6] = m;
  __syncthreads();
  if (tid == 0) {
    float mm = fmaxf(fmaxf(sred[0], sred[1]), fmaxf(sred[2], sred[3]));
    sscal = mm;
  }
  __syncthreads();
  const float mx = sscal;

  float s = 0.f;
  for (int i = tid; i < L_; i += 256) {
    float e = __expf(sl[i] - mx);
    sl[i] = e;
    s += e;
  }
#pragma unroll
  for (int off = 32; off > 0; off >>= 1) s += __shfl_xor(s, off);
  if ((tid & 63) == 0) sred[tid >> 6] = s;
  __syncthreads();
  if (tid == 0) {
    sscal = 1.0f / ((sred[0] + sred[1]) + (sred[2] + sred[3]));
  }
  __syncthreads();
  const float inv = sscal;

  // PV over 32 cols: 8 float4-cols x 32 l-subsets
  const int dq4  = tid & 7;
  const int lsub = tid >> 3;
  const float4* vp = (const float4*)(values + (size_t)b * H_ + head * DK + dpart * 32) + dq4;
  float4 acc = {0.f, 0.f, 0.f, 0.f};
  for (int ll = lsub; ll < L_; ll += 32) {
    const float w = sl[ll];
    float4 v = vp[(size_t)ll * (B_ * H_ / 4)];
    acc.x += w * v.x; acc.y += w * v.y; acc.z += w * v.z; acc.w += w * v.w;
  }
  pacc[lsub][dq4] = acc;
  __syncthreads();
  if (tid < 64) {
    const int q = tid & 7, k = tid >> 3;
    float4 a0 = pacc[k][q], a1 = pacc[k + 8][q], a2 = pacc[k + 16][q], a3 = pacc[k + 24][q];
    float4 r;
    r.x = (a0.x + a1.x) + (a2.x + a3.x);
    r.y = (a0.y + a1.y) + (a2.y + a3.y);
    r.z = (a0.z + a1.z) + (a2.z + a3.z);
    r.w = (a0.w + a1.w) + (a2.w + a3.w);
    pacc[k][q] = r;
  }
  __syncthreads();
  if (tid < 8) {
    float4 t = {0.f, 0.f, 0.f, 0.f};
#pragma unroll
    for (int k = 0; k < 8; ++k) {
      float4 a = pacc[k][tid];
      t.x += a.x; t.y += a.y; t.z += a.z; t.w += a.w;
    }
    t.x *= inv; t.y *= inv; t.z *= inv; t.w *= inv;
    *(float4*)(out + (size_t)b * H_ + head * DK + dpart * 32 + tid * 4) = t;
  }
}

// ---------------------------------------------------------------------------
extern "C" void kernel_launch(void* const* d_in, const int* in_sizes, int n_in,
                              void* d_out, int out_size, void* d_ws, size_t ws_size,
                              hipStream_t stream) {
  const float* query  = (const float*)d_in[0];
  const float* feed   = (const float*)d_in[1];
  const float* values = (const float*)d_in[2];
  const float* attn_w = (const float*)d_in[3];
  const float* bias   = (const float*)d_in[4];
  const float* score  = (const float*)d_in[5];
  float* out = (float*)d_out;

  // Workspace: qs2 (2 MB float2) | wk8 (256 KB e4m3) | logits[2] (2x512 KB)
  float2*        qs2    = (float2*)d_ws;
  unsigned char* wk8    = (unsigned char*)d_ws + (size_t)(B_ * HEADS * H_) * sizeof(float2);
  float*         logits = (float*)(wk8 + (size_t)H_ * DK);

  prep_kernel<<<144, 256, 0, stream>>>(query, attn_w, bias, score, qs2, wk8);
  logits_kernel<<<dim3(L_ / 512, B_ * HEADS, 2), 256, 0, stream>>>(feed, wk8, qs2, logits);
  softmax_pv_kernel<<<dim3(B_ * HEADS, 4), 256, 0, stream>>>(logits, values, out);
}

// Round 24
// 123.243 us; speedup vs baseline: 1.0115x; 1.0115x over previous
//
#include <hip/hip_runtime.h>
#include <hip/hip_bf16.h>
#include <hip/hip_fp8.h>

#define HEADS 16
#define B_    8
#define H_    2048
#define L_    1024
#define DK    128   // H_/HEADS

typedef __attribute__((ext_vector_type(8))) int   i32x8;
typedef __attribute__((ext_vector_type(4))) int   i32x4;
typedef __attribute__((ext_vector_type(4))) float f32x4;

__device__ __forceinline__ unsigned u8e4m3(float x) {
  __hip_fp8_e4m3 f8(x);
  return (unsigned)f8.__x;
}

// async global->LDS, 16 B per lane: global src per-lane, LDS dest wave-uniform
__device__ __forceinline__ void gload_lds16(const void* g, void* l) {
  __builtin_amdgcn_global_load_lds(
      (const __attribute__((address_space(1))) void*)g,
      (__attribute__((address_space(3))) void*)l, 16, 0, 0);
}

// ---------------------------------------------------------------------------
// Kernel 0 (merged preps).
// Blocks 0..127:   qs2[bh][j] = { 64*(q.Wq + bias)[j], score[j]/64 }  (float2)
// Blocks 128..143: wk8 fp8-fragment pack of 64*Wk (e4m3):
//   lane-slot (nc, l): n = nc*16 + (l&15), k = (l>>4)*32 + i (i=0..31)
//   storage: wk8[nc*2048 + (i<16?0:1024) + l*16 + (i&15)]
// ---------------------------------------------------------------------------
__global__ void __launch_bounds__(256)
prep_kernel(const float* __restrict__ query,
            const float* __restrict__ attn_w,
            const float* __restrict__ bias,
            const float* __restrict__ score,
            float2* __restrict__ qs2,
            unsigned char* __restrict__ wk8) {
  const int tid = threadIdx.x;
  if (blockIdx.x < 128) {
    const int jt = blockIdx.x & 7;    // j-tile
    const int bg = blockIdx.x >> 3;   // bh-group of 8
    __shared__ float qv[8][DK];
    for (int i = tid; i < 8 * DK; i += 256) {
      const int bh = bg * 8 + (i >> 7);
      const int d  = i & 127;
      const int b = bh >> 4, head = bh & 15;
      qv[i >> 7][d] = query[b * H_ + head * DK + d];
    }
    __syncthreads();
    const int j = jt * 256 + tid;
    const float bj = bias[j];
    const float sj = score[j] * (1.0f / 64.0f);
    float acc[8];
#pragma unroll
    for (int u = 0; u < 8; ++u) acc[u] = bj;
    for (int d = 0; d < DK; ++d) {
      const float wv = attn_w[d * H_ + j];
#pragma unroll
      for (int u = 0; u < 8; ++u) acc[u] += qv[u][d] * wv;
    }
#pragma unroll
    for (int u = 0; u < 8; ++u) {
      float2 t; t.x = 64.0f * acc[u]; t.y = sj;
      qs2[(size_t)(bg * 8 + u) * H_ + j] = t;
    }
  } else {
    const int t0 = (blockIdx.x - 128) * 256 + tid;   // 0..4095
    for (int tt = t0; tt < 8192; tt += 4096) {       // lane-slots
      const int l  = tt & 63;
      const int nc = tt >> 6;
      const int n  = nc * 16 + (l & 15);
      const int k0 = (l >> 4) * 32;
#pragma unroll
      for (int half = 0; half < 2; ++half) {
        unsigned w[4];
#pragma unroll
        for (int j = 0; j < 4; ++j) {
          unsigned v = 0;
#pragma unroll
          for (int byt = 0; byt < 4; ++byt) {
            const int i = half * 16 + j * 4 + byt;
            const float x = 64.0f * attn_w[(size_t)(DK + k0 + i) * H_ + n];
            v |= u8e4m3(x) << (8 * byt);
          }
          w[j] = v;
        }
        uint4 q; q.x = w[0]; q.y = w[1]; q.z = w[2]; q.w = w[3];
        *(uint4*)(wk8 + (size_t)nc * 2048 + half * 1024 + l * 16) = q;
      }
    }
  }
}

// ---------------------------------------------------------------------------
// Kernel 1: partial logits over one H-half (MX-fp8 K=128, scales=1.0).
// 128 rows/wave (aF[8] = 64 VGPR), ANTI-SPILL epilogue: each chunk's 8 MFMAs
// run as TWO sequential groups of 4 with named d0..d3 reused (r22's proven
// 128-VGPR codegen shape, twice per chunk) — live set ~170, no d[8] batch.
// Block = 4 waves x 128 rows = 512 rows of one bh, one H-half (z-split).
// r22's proven ring schedule: 4-slot x 16KB ring, phase = 8 chunks,
// counted vmcnt(8) + 1 raw barrier/phase. LDS 72KB -> 2 blocks/CU.
// ---------------------------------------------------------------------------
__global__ void __launch_bounds__(256)
logits_kernel(const float* __restrict__ feed,
              const unsigned char* __restrict__ wk8,
              const float2* __restrict__ qs2,
              float* __restrict__ logits) {
  const int ltile = blockIdx.x;     // 0..1 (512 rows each)
  const int bh    = blockIdx.y;     // 0..127
  const int nblk  = blockIdx.z;     // 0..1 (H halves)
  const int b     = bh >> 4;
  const int head  = bh & 15;
  const int tid   = threadIdx.x;
  const int wave  = tid >> 6;
  const int lane  = tid & 63;
  const int row   = lane & 15;      // A row / B col / D col
  const int g     = lane >> 4;      // k-group 0..3 (32 k each)

  __shared__ unsigned char ring[4][16384]; // 4 slots x 16KB (phase = 8 chunks)
  __shared__ float2 qs[1024];              // {64*qwb, score/64} half: 8 KB

  // ---- stage qs for this half (block-cooperative) ----
#pragma unroll
  for (int u = 0; u < 4; ++u)
    qs[tid + 256 * u] = qs2[(size_t)bh * H_ + nblk * 1024 + tid + 256 * u];

  // ---- A fragments: 8 subtiles (128 rows), e4m3-packed, resident ----
  i32x8 aF[8];
#pragma unroll
  for (int s = 0; s < 8; ++s) {
    const int l = ltile * 512 + wave * 128 + s * 16 + row;
    const float* fh = feed + (size_t)l * (B_ * H_) + b * H_ + head * DK + g * 32;
    i32x8 af;
#pragma unroll
    for (int j = 0; j < 8; ++j) {
      float4 x = *(const float4*)(fh + j * 4);
      unsigned v = u8e4m3(x.x) | (u8e4m3(x.y) << 8) |
                   (u8e4m3(x.z) << 16) | (u8e4m3(x.w) << 24);
      af[j] = (int)v;
    }
    aF[s] = af;
  }
  __syncthreads();   // qs visible; drains ALL prologue VMEM -> in-loop vmcnt
                     // counts only the staging gloads.

  const char* wkb   = (const char*)wk8 + (size_t)nblk * 131072;  // half base
  char*       ringb = (char*)ring;
  const int   seg0  = wave * 4096;   // this wave's 4KB segment per phase

  // ---- ring prologue: phases 0,1 into slots 0,1 (4 gloads each/wave) ----
#pragma unroll
  for (int ph = 0; ph < 2; ++ph) {
#pragma unroll
    for (int i = 0; i < 4; ++i)
      gload_lds16(wkb + (size_t)ph * 16384 + seg0 + i * 1024 + lane * 16,
                  ringb + ph * 16384 + seg0 + i * 1024);
  }

  float lacc[8][4] = {};

#pragma unroll 1
  for (int p = 0; p < 8; ++p) {
    // stage phase p+2 (4-slot ring, lookahead 2 — r7/r19/r22-proven race-free)
    const int pf = (p + 2 < 8) ? p + 2 : 7;
    const int ws = ((p + 2) & 3) * 16384;
#pragma unroll
    for (int i = 0; i < 4; ++i)
      gload_lds16(wkb + (size_t)pf * 16384 + seg0 + i * 1024 + lane * 16,
                  ringb + ws + seg0 + i * 1024);

    __builtin_amdgcn_sched_barrier(0);
    // own phase-p loads landed (phases p+1, p+2 = 8 loads stay in flight)
    asm volatile("s_waitcnt vmcnt(8)" ::: "memory");
    __builtin_amdgcn_s_barrier();        // all waves' phase-p loads landed
    __builtin_amdgcn_sched_barrier(0);

    const char* rs = ringb + (p & 3) * 16384;
#pragma unroll
    for (int cc = 0; cc < 8; ++cc) {
      const char* rc = rs + cc * 2048 + lane * 16;
      i32x4 lo = *(const i32x4*)(rc);
      i32x4 hi = *(const i32x4*)(rc + 1024);
      i32x8 b8;
      b8[0] = lo[0]; b8[1] = lo[1]; b8[2] = lo[2]; b8[3] = lo[3];
      b8[4] = hi[0]; b8[5] = hi[1]; b8[6] = hi[2]; b8[7] = hi[3];
      const float2 q2 = qs[(8 * p + cc) * 16 + row];
      const float qx = q2.x, qy = q2.y;

      // group 0: subtiles 0..3 (4 independent full-K MFMAs)
      {
        f32x4 d0 = {qx, qx, qx, qx};
        f32x4 d1 = {qx, qx, qx, qx};
        f32x4 d2 = {qx, qx, qx, qx};
        f32x4 d3 = {qx, qx, qx, qx};
        d0 = __builtin_amdgcn_mfma_scale_f32_16x16x128_f8f6f4(
               aF[0], b8, d0, 0, 0, 0, 0x7F7F7F7F, 0, 0x7F7F7F7F);
        d1 = __builtin_amdgcn_mfma_scale_f32_16x16x128_f8f6f4(
               aF[1], b8, d1, 0, 0, 0, 0x7F7F7F7F, 0, 0x7F7F7F7F);
        d2 = __builtin_amdgcn_mfma_scale_f32_16x16x128_f8f6f4(
               aF[2], b8, d2, 0, 0, 0, 0x7F7F7F7F, 0, 0x7F7F7F7F);
        d3 = __builtin_amdgcn_mfma_scale_f32_16x16x128_f8f6f4(
               aF[3], b8, d3, 0, 0, 0, 0x7F7F7F7F, 0, 0x7F7F7F7F);
#pragma unroll
        for (int i = 0; i < 4; ++i) {
          lacc[0][i] += fmaxf(d0[i], 0.f) * qy;
          lacc[1][i] += fmaxf(d1[i], 0.f) * qy;
          lacc[2][i] += fmaxf(d2[i], 0.f) * qy;
          lacc[3][i] += fmaxf(d3[i], 0.f) * qy;
        }
      }
      // group 1: subtiles 4..7
      {
        f32x4 d0 = {qx, qx, qx, qx};
        f32x4 d1 = {qx, qx, qx, qx};
        f32x4 d2 = {qx, qx, qx, qx};
        f32x4 d3 = {qx, qx, qx, qx};
        d0 = __builtin_amdgcn_mfma_scale_f32_16x16x128_f8f6f4(
               aF[4], b8, d0, 0, 0, 0, 0x7F7F7F7F, 0, 0x7F7F7F7F);
        d1 = __builtin_amdgcn_mfma_scale_f32_16x16x128_f8f6f4(
               aF[5], b8, d1, 0, 0, 0, 0x7F7F7F7F, 0, 0x7F7F7F7F);
        d2 = __builtin_amdgcn_mfma_scale_f32_16x16x128_f8f6f4(
               aF[6], b8, d2, 0, 0, 0, 0x7F7F7F7F, 0, 0x7F7F7F7F);
        d3 = __builtin_amdgcn_mfma_scale_f32_16x16x128_f8f6f4(
               aF[7], b8, d3, 0, 0, 0, 0x7F7F7F7F, 0, 0x7F7F7F7F);
#pragma unroll
        for (int i = 0; i < 4; ++i) {
          lacc[4][i] += fmaxf(d0[i], 0.f) * qy;
          lacc[5][i] += fmaxf(d1[i], 0.f) * qy;
          lacc[6][i] += fmaxf(d2[i], 0.f) * qy;
          lacc[7][i] += fmaxf(d3[i], 0.f) * qy;
        }
      }
    }
  }

  // ---- reduce over the 16 D-columns, write partial logits ----
#pragma unroll
  for (int s = 0; s < 8; ++s) {
#pragma unroll
    for (int i = 0; i < 4; ++i) {
      float v = lacc[s][i];
#pragma unroll
      for (int off = 1; off < 16; off <<= 1) v += __shfl_xor(v, off);
      lacc[s][i] = v;
    }
  }
  if (row == 0) {
    float* lout = logits + (size_t)nblk * (128 * L_);
#pragma unroll
    for (int s = 0; s < 8; ++s) {
      const int base = bh * L_ + ltile * 512 + wave * 128 + s * 16 + g * 4;
#pragma unroll
      for (int i = 0; i < 4; ++i) lout[base + i] = lacc[s][i];
    }
  }
}

// ---------------------------------------------------------------------------
// Kernel 2: grid (bh, dpart): softmax over L (sum of the two H-half partial
// buffers, redundant per dpart), then out[d] over 32 d-columns. float4 reads.
// ---------------------------------------------------------------------------
__global__ void __launch_bounds__(256)
softmax_pv_kernel(const float* __restrict__ logits,
                  const float* __restrict__ values,
                  float* __restrict__ out) {
  const int bh    = blockIdx.x;   // 0..127
  const int dpart = blockIdx.y;   // 0..3  (32 d-cols each)
  const int b     = bh >> 4;
  const int head  = bh & 15;
  const int tid   = threadIdx.x;

  __shared__ float  sl[L_];
  __shared__ float  sred[4];
  __shared__ float  sscal;
  __shared__ float4 pacc[32][8];

  float m = -1e30f;
  for (int i = tid; i < L_; i += 256) {
    float v = logits[(size_t)bh * L_ + i] +
              logits[(size_t)(128 * L_) + bh * L_ + i];
    sl[i] = v;
    m = fmaxf(m, v);
  }
#pragma unroll
  for (int off = 32; off > 0; off >>= 1) m = fmaxf(m, __shfl_xor(m, off));
  if ((tid & 63) == 0) sred[tid >> 6] = m;
  __syncthreads();
  if (tid == 0) {
    float mm = fmaxf(fmaxf(sred[0], sred[1]), fmaxf(sred[2], sred[3]));
    sscal = mm;
  }
  __syncthreads();
  const float mx = sscal;

  float s = 0.f;
  for (int i = tid; i < L_; i += 256) {
    float e = __expf(sl[i] - mx);
    sl[i] = e;
    s += e;
  }
#pragma unroll
  for (int off = 32; off > 0; off >>= 1) s += __shfl_xor(s, off);
  if ((tid & 63) == 0) sred[tid >> 6] = s;
  __syncthreads();
  if (tid == 0) {
    sscal = 1.0f / ((sred[0] + sred[1]) + (sred[2] + sred[3]));
  }
  __syncthreads();
  const float inv = sscal;

  // PV over 32 cols: 8 float4-cols x 32 l-subsets
  const int dq4  = tid & 7;
  const int lsub = tid >> 3;
  const float4* vp = (const float4*)(values + (size_t)b * H_ + head * DK + dpart * 32) + dq4;
  float4 acc = {0.f, 0.f, 0.f, 0.f};
  for (int ll = lsub; ll < L_; ll += 32) {
    const float w = sl[ll];
    float4 v = vp[(size_t)ll * (B_ * H_ / 4)];
    acc.x += w * v.x; acc.y += w * v.y; acc.z += w * v.z; acc.w += w * v.w;
  }
  pacc[lsub][dq4] = acc;
  __syncthreads();
  if (tid < 64) {
    const int q = tid & 7, k = tid >> 3;
    float4 a0 = pacc[k][q], a1 = pacc[k + 8][q], a2 = pacc[k + 16][q], a3 = pacc[k + 24][q];
    float4 r;
    r.x = (a0.x + a1.x) + (a2.x + a3.x);
    r.y = (a0.y + a1.y) + (a2.y + a3.y);
    r.z = (a0.z + a1.z) + (a2.z + a3.z);
    r.w = (a0.w + a1.w) + (a2.w + a3.w);
    pacc[k][q] = r;
  }
  __syncthreads();
  if (tid < 8) {
    float4 t = {0.f, 0.f, 0.f, 0.f};
#pragma unroll
    for (int k = 0; k < 8; ++k) {
      float4 a = pacc[k][tid];
      t.x += a.x; t.y += a.y; t.z += a.z; t.w += a.w;
    }
    t.x *= inv; t.y *= inv; t.z *= inv; t.w *= inv;
    *(float4*)(out + (size_t)b * H_ + head * DK + dpart * 32 + tid * 4) = t;
  }
}

// ---------------------------------------------------------------------------
extern "C" void kernel_launch(void* const* d_in, const int* in_sizes, int n_in,
                              void* d_out, int out_size, void* d_ws, size_t ws_size,
                              hipStream_t stream) {
  const float* query  = (const float*)d_in[0];
  const float* feed   = (const float*)d_in[1];
  const float* values = (const float*)d_in[2];
  const float* attn_w = (const float*)d_in[3];
  const float* bias   = (const float*)d_in[4];
  const float* score  = (const float*)d_in[5];
  float* out = (float*)d_out;

  // Workspace: qs2 (2 MB float2) | wk8 (256 KB e4m3) | logits[2] (2x512 KB)
  float2*        qs2    = (float2*)d_ws;
  unsigned char* wk8    = (unsigned char*)d_ws + (size_t)(B_ * HEADS * H_) * sizeof(float2);
  float*         logits = (float*)(wk8 + (size_t)H_ * DK);

  prep_kernel<<<144, 256, 0, stream>>>(query, attn_w, bias, score, qs2, wk8);
  logits_kernel<<<dim3(L_ / 512, B_ * HEADS, 2), 256, 0, stream>>>(feed, wk8, qs2, logits);
  softmax_pv_kernel<<<dim3(B_ * HEADS, 4), 256, 0, stream>>>(logits, values, out);
}

// Round 25
// 80.539 us; speedup vs baseline: 1.5478x; 1.5302x over previous
//
#include <hip/hip_runtime.h>
#include <hip/hip_bf16.h>
#include <hip/hip_fp8.h>

#define HEADS 16
#define B_    8
#define H_    2048
#define L_    1024
#define DK    128   // H_/HEADS

typedef __attribute__((ext_vector_type(8))) int   i32x8;
typedef __attribute__((ext_vector_type(4))) int   i32x4;
typedef __attribute__((ext_vector_type(4))) float f32x4;

__device__ __forceinline__ unsigned u8e4m3(float x) {
  __hip_fp8_e4m3 f8(x);
  return (unsigned)f8.__x;
}

// async global->LDS, 16 B per lane: global src per-lane, LDS dest wave-uniform
__device__ __forceinline__ void gload_lds16(const void* g, void* l) {
  __builtin_amdgcn_global_load_lds(
      (const __attribute__((address_space(1))) void*)g,
      (__attribute__((address_space(3))) void*)l, 16, 0, 0);
}

// ---------------------------------------------------------------------------
// Kernel 0 (merged preps).
// Blocks 0..127:   qs2[bh][j] = { 64*(q.Wq + bias)[j], score[j]/64 }  (float2)
// Blocks 128..143: wk8 fp8-fragment pack of 64*Wk (e4m3):
//   lane-slot (nc, l): n = nc*16 + (l&15), k = (l>>4)*32 + i (i=0..31)
//   storage: wk8[nc*2048 + (i<16?0:1024) + l*16 + (i&15)]
// ---------------------------------------------------------------------------
__global__ void __launch_bounds__(256)
prep_kernel(const float* __restrict__ query,
            const float* __restrict__ attn_w,
            const float* __restrict__ bias,
            const float* __restrict__ score,
            float2* __restrict__ qs2,
            unsigned char* __restrict__ wk8) {
  const int tid = threadIdx.x;
  if (blockIdx.x < 128) {
    const int jt = blockIdx.x & 7;    // j-tile
    const int bg = blockIdx.x >> 3;   // bh-group of 8
    __shared__ float qv[8][DK];
    for (int i = tid; i < 8 * DK; i += 256) {
      const int bh = bg * 8 + (i >> 7);
      const int d  = i & 127;
      const int b = bh >> 4, head = bh & 15;
      qv[i >> 7][d] = query[b * H_ + head * DK + d];
    }
    __syncthreads();
    const int j = jt * 256 + tid;
    const float bj = bias[j];
    const float sj = score[j] * (1.0f / 64.0f);
    float acc[8];
#pragma unroll
    for (int u = 0; u < 8; ++u) acc[u] = bj;
    for (int d = 0; d < DK; ++d) {
      const float wv = attn_w[d * H_ + j];
#pragma unroll
      for (int u = 0; u < 8; ++u) acc[u] += qv[u][d] * wv;
    }
#pragma unroll
    for (int u = 0; u < 8; ++u) {
      float2 t; t.x = 64.0f * acc[u]; t.y = sj;
      qs2[(size_t)(bg * 8 + u) * H_ + j] = t;
    }
  } else {
    const int t0 = (blockIdx.x - 128) * 256 + tid;   // 0..4095
    for (int tt = t0; tt < 8192; tt += 4096) {       // lane-slots
      const int l  = tt & 63;
      const int nc = tt >> 6;
      const int n  = nc * 16 + (l & 15);
      const int k0 = (l >> 4) * 32;
#pragma unroll
      for (int half = 0; half < 2; ++half) {
        unsigned w[4];
#pragma unroll
        for (int j = 0; j < 4; ++j) {
          unsigned v = 0;
#pragma unroll
          for (int byt = 0; byt < 4; ++byt) {
            const int i = half * 16 + j * 4 + byt;
            const float x = 64.0f * attn_w[(size_t)(DK + k0 + i) * H_ + n];
            v |= u8e4m3(x) << (8 * byt);
          }
          w[j] = v;
        }
        uint4 q; q.x = w[0]; q.y = w[1]; q.z = w[2]; q.w = w[3];
        *(uint4*)(wk8 + (size_t)nc * 2048 + half * 1024 + l * 16) = q;
      }
    }
  }
}

// ---------------------------------------------------------------------------
// Kernel 1: logits[bh][l] = sum_n relu( (K Wk)[l][n] + qwb[bh][n] ) * score[n]
// Best verified configuration (r22): MX-fp8 K=128 (scales=1.0), block =
// 4 waves x 64 rows = 256 rows of one bh; 4-slot x 16KB LDS ring staged by
// global_load_lds (phase = 8 chunks, 16 phases); counted s_waitcnt vmcnt(8)
// + one raw s_barrier per phase (never vmcnt(0) in-loop). A = e4m3(feed)
// resident in registers; B = e4m3(64*Wk) staged; qwb'=64*qwb,
// score'=score/64 fold the fp8 scaling out exactly.
// ---------------------------------------------------------------------------
__global__ void __launch_bounds__(256, 2)
logits_kernel(const float* __restrict__ feed,
              const unsigned char* __restrict__ wk8,
              const float2* __restrict__ qs2,
              float* __restrict__ logits) {
  const int ltile = blockIdx.x;     // 0..3 (256 rows each)
  const int bh    = blockIdx.y;     // 0..127
  const int b     = bh >> 4;
  const int head  = bh & 15;
  const int tid   = threadIdx.x;
  const int wave  = tid >> 6;
  const int lane  = tid & 63;
  const int row   = lane & 15;      // A row / B col / D col
  const int g     = lane >> 4;      // k-group 0..3 (32 k each)

  __shared__ unsigned char ring[4][16384]; // 4 slots x 16KB (phase = 8 chunks)
  __shared__ float2 qs[H_];                // {64*qwb, score/64}: 16 KB

  // ---- stage qs (block-cooperative) ----
#pragma unroll
  for (int u = 0; u < 8; ++u)
    qs[tid + 256 * u] = qs2[(size_t)bh * H_ + tid + 256 * u];

  // ---- A fragments: 4 subtiles, e4m3-packed, resident (32 VGPR) ----
  i32x8 aF[4];
#pragma unroll
  for (int s = 0; s < 4; ++s) {
    const int l = ltile * 256 + wave * 64 + s * 16 + row;
    const float* fh = feed + (size_t)l * (B_ * H_) + b * H_ + head * DK + g * 32;
    i32x8 af;
#pragma unroll
    for (int j = 0; j < 8; ++j) {
      float4 x = *(const float4*)(fh + j * 4);
      unsigned v = u8e4m3(x.x) | (u8e4m3(x.y) << 8) |
                   (u8e4m3(x.z) << 16) | (u8e4m3(x.w) << 24);
      af[j] = (int)v;
    }
    aF[s] = af;
  }
  __syncthreads();   // qs visible; drains ALL prologue VMEM -> in-loop vmcnt
                     // counts only the staging gloads.

  const char* wkb   = (const char*)wk8;
  char*       ringb = (char*)ring;
  const int   seg0  = wave * 4096;   // this wave's 4KB segment per phase

  // ---- ring prologue: phases 0,1 into slots 0,1 (4 gloads each/wave) ----
#pragma unroll
  for (int ph = 0; ph < 2; ++ph) {
#pragma unroll
    for (int i = 0; i < 4; ++i)
      gload_lds16(wkb + (size_t)ph * 16384 + seg0 + i * 1024 + lane * 16,
                  ringb + ph * 16384 + seg0 + i * 1024);
  }

  float lacc[4][4] = {};

#pragma unroll 1
  for (int p = 0; p < 16; ++p) {
    // stage phase p+2 (4-slot ring, lookahead 2 — clamped tail re-issues land
    // in slots whose readers finished >=2 barriers ago; race-free)
    const int pf = (p + 2 < 16) ? p + 2 : 15;
    const int ws = ((p + 2) & 3) * 16384;
#pragma unroll
    for (int i = 0; i < 4; ++i)
      gload_lds16(wkb + (size_t)pf * 16384 + seg0 + i * 1024 + lane * 16,
                  ringb + ws + seg0 + i * 1024);

    __builtin_amdgcn_sched_barrier(0);
    // own phase-p loads landed (phases p+1, p+2 = 8 loads stay in flight)
    asm volatile("s_waitcnt vmcnt(8)" ::: "memory");
    __builtin_amdgcn_s_barrier();        // all waves' phase-p loads landed
    __builtin_amdgcn_sched_barrier(0);

    const char* rs = ringb + (p & 3) * 16384;
#pragma unroll
    for (int cc = 0; cc < 8; ++cc) {
      const char* rc = rs + cc * 2048 + lane * 16;
      i32x4 lo = *(const i32x4*)(rc);
      i32x4 hi = *(const i32x4*)(rc + 1024);
      i32x8 b8;
      b8[0] = lo[0]; b8[1] = lo[1]; b8[2] = lo[2]; b8[3] = lo[3];
      b8[4] = hi[0]; b8[5] = hi[1]; b8[6] = hi[2]; b8[7] = hi[3];
      const float2 q2 = qs[(8 * p + cc) * 16 + row];
      const float qx = q2.x, qy = q2.y;

      // 4 INDEPENDENT full-K MFMAs (scales = 1.0 -> plain fp8 K=128 GEMM)
      f32x4 d0 = {qx, qx, qx, qx};
      f32x4 d1 = {qx, qx, qx, qx};
      f32x4 d2 = {qx, qx, qx, qx};
      f32x4 d3 = {qx, qx, qx, qx};
      d0 = __builtin_amdgcn_mfma_scale_f32_16x16x128_f8f6f4(
             aF[0], b8, d0, 0, 0, 0, 0x7F7F7F7F, 0, 0x7F7F7F7F);
      d1 = __builtin_amdgcn_mfma_scale_f32_16x16x128_f8f6f4(
             aF[1], b8, d1, 0, 0, 0, 0x7F7F7F7F, 0, 0x7F7F7F7F);
      d2 = __builtin_amdgcn_mfma_scale_f32_16x16x128_f8f6f4(
             aF[2], b8, d2, 0, 0, 0, 0x7F7F7F7F, 0, 0x7F7F7F7F);
      d3 = __builtin_amdgcn_mfma_scale_f32_16x16x128_f8f6f4(
             aF[3], b8, d3, 0, 0, 0, 0x7F7F7F7F, 0, 0x7F7F7F7F);

#pragma unroll
      for (int i = 0; i < 4; ++i) {
        lacc[0][i] += fmaxf(d0[i], 0.f) * qy;
        lacc[1][i] += fmaxf(d1[i], 0.f) * qy;
        lacc[2][i] += fmaxf(d2[i], 0.f) * qy;
        lacc[3][i] += fmaxf(d3[i], 0.f) * qy;
      }
    }
  }

  // ---- reduce over the 16 D-columns, write logits ----
#pragma unroll
  for (int s = 0; s < 4; ++s) {
#pragma unroll
    for (int i = 0; i < 4; ++i) {
      float v = lacc[s][i];
#pragma unroll
      for (int off = 1; off < 16; off <<= 1) v += __shfl_xor(v, off);
      lacc[s][i] = v;
    }
  }
  if (row == 0) {
#pragma unroll
    for (int s = 0; s < 4; ++s) {
      const int base = bh * L_ + ltile * 256 + wave * 64 + s * 16 + g * 4;
#pragma unroll
      for (int i = 0; i < 4; ++i) logits[base + i] = lacc[s][i];
    }
  }
}

// ---------------------------------------------------------------------------
// Kernel 2: grid (bh, dpart): softmax over L (redundant per dpart, cheap),
// then out[d] over this block's 32 d-columns. values read as float4.
// (At HBM roofline for the values read — ~10.5us floor.)
// ---------------------------------------------------------------------------
__global__ void __launch_bounds__(256)
softmax_pv_kernel(const float* __restrict__ logits,
                  const float* __restrict__ values,
                  float* __restrict__ out) {
  const int bh    = blockIdx.x;   // 0..127
  const int dpart = blockIdx.y;   // 0..3  (32 d-cols each)
  const int b     = bh >> 4;
  const int head  = bh & 15;
  const int tid   = threadIdx.x;

  __shared__ float  sl[L_];
  __shared__ float  sred[4];
  __shared__ float  sscal;
  __shared__ float4 pacc[32][8];

  float m = -1e30f;
  for (int i = tid; i < L_; i += 256) {
    float v = logits[(size_t)bh * L_ + i];
    sl[i] = v;
    m = fmaxf(m, v);
  }
#pragma unroll
  for (int off = 32; off > 0; off >>= 1) m = fmaxf(m, __shfl_xor(m, off));
  if ((tid & 63) == 0) sred[tid >> 6] = m;
  __syncthreads();
  if (tid == 0) {
    float mm = fmaxf(fmaxf(sred[0], sred[1]), fmaxf(sred[2], sred[3]));
    sscal = mm;
  }
  __syncthreads();
  const float mx = sscal;

  float s = 0.f;
  for (int i = tid; i < L_; i += 256) {
    float e = __expf(sl[i] - mx);
    sl[i] = e;
    s += e;
  }
#pragma unroll
  for (int off = 32; off > 0; off >>= 1) s += __shfl_xor(s, off);
  if ((tid & 63) == 0) sred[tid >> 6] = s;
  __syncthreads();
  if (tid == 0) {
    sscal = 1.0f / ((sred[0] + sred[1]) + (sred[2] + sred[3]));
  }
  __syncthreads();
  const float inv = sscal;

  // PV over 32 cols: 8 float4-cols x 32 l-subsets
  const int dq4  = tid & 7;
  const int lsub = tid >> 3;
  const float4* vp = (const float4*)(values + (size_t)b * H_ + head * DK + dpart * 32) + dq4;
  float4 acc = {0.f, 0.f, 0.f, 0.f};
  for (int ll = lsub; ll < L_; ll += 32) {
    const float w = sl[ll];
    float4 v = vp[(size_t)ll * (B_ * H_ / 4)];
    acc.x += w * v.x; acc.y += w * v.y; acc.z += w * v.z; acc.w += w * v.w;
  }
  pacc[lsub][dq4] = acc;
  __syncthreads();
  if (tid < 64) {
    const int q = tid & 7, k = tid >> 3;
    float4 a0 = pacc[k][q], a1 = pacc[k + 8][q], a2 = pacc[k + 16][q], a3 = pacc[k + 24][q];
    float4 r;
    r.x = (a0.x + a1.x) + (a2.x + a3.x);
    r.y = (a0.y + a1.y) + (a2.y + a3.y);
    r.z = (a0.z + a1.z) + (a2.z + a3.z);
    r.w = (a0.w + a1.w) + (a2.w + a3.w);
    pacc[k][q] = r;
  }
  __syncthreads();
  if (tid < 8) {
    float4 t = {0.f, 0.f, 0.f, 0.f};
#pragma unroll
    for (int k = 0; k < 8; ++k) {
      float4 a = pacc[k][tid];
      t.x += a.x; t.y += a.y; t.z += a.z; t.w += a.w;
    }
    t.x *= inv; t.y *= inv; t.z *= inv; t.w *= inv;
    *(float4*)(out + (size_t)b * H_ + head * DK + dpart * 32 + tid * 4) = t;
  }
}

// ---------------------------------------------------------------------------
extern "C" void kernel_launch(void* const* d_in, const int* in_sizes, int n_in,
                              void* d_out, int out_size, void* d_ws, size_t ws_size,
                              hipStream_t stream) {
  const float* query  = (const float*)d_in[0];
  const float* feed   = (const float*)d_in[1];
  const float* values = (const float*)d_in[2];
  const float* attn_w = (const float*)d_in[3];
  const float* bias   = (const float*)d_in[4];
  const float* score  = (const float*)d_in[5];
  float* out = (float*)d_out;

  // Workspace: qs2 (2 MB float2) | wk8 (256 KB e4m3) | logits (512 KB f32)
  float2*        qs2    = (float2*)d_ws;
  unsigned char* wk8    = (unsigned char*)d_ws + (size_t)(B_ * HEADS * H_) * sizeof(float2);
  float*         logits = (float*)(wk8 + (size_t)H_ * DK);

  prep_kernel<<<144, 256, 0, stream>>>(query, attn_w, bias, score, qs2, wk8);
  logits_kernel<<<dim3(L_ / 256, B_ * HEADS), 256, 0, stream>>>(feed, wk8, qs2, logits);
  softmax_pv_kernel<<<dim3(B_ * HEADS, 4), 256, 0, stream>>>(logits, values, out);
}